// Round 12
// baseline (288.891 us; speedup 1.0000x reference)
//
#include <hip/hip_runtime.h>

#define EPS 1e-5f
#define NIN 9
#define F1 32
#define F2 64
#define ROWB 80       // bytes per bf16 f1 row in LDS staging
#define SHIFT 7       // coarse bucket = seg >> 7 (128 segs/bucket)
#define NSEGB 128     // segs per bucket
#define NBMAX 1024
#define BT_BIN 4096   // points per count/binning slice
#define WSTRIDE 68    // dwords per window row (padded)
#define NREP 32       // atomic-target replicas

// params region float offsets (ws)
#define WS_SC1  192
#define WS_SH1  224
#define WS_W1P  256

typedef __attribute__((ext_vector_type(8))) short bf16x8;
typedef __attribute__((ext_vector_type(4))) float f32x4;

__device__ __forceinline__ unsigned int f2bf(float f) {
    unsigned int u = __float_as_uint(f);
    return (u + 0x7fffu + ((u >> 16) & 1u)) >> 16;   // RNE
}
__device__ __forceinline__ unsigned int pack2(float lo, float hi) {
    unsigned int r;
    asm("v_cvt_pk_bf16_f32 %0, %1, %2" : "=v"(r) : "v"(lo), "v"(hi));
    return r;
}

// 9-float point row in 3 vmem instructions (2x dwordx4 + 1 dword)
__device__ __forceinline__ void load_pt9(const float* __restrict__ p, float* __restrict__ x)
{
    const float4* p4 = (const float4*)p;
    const float4 a = p4[0];
    const float4 b = p4[1];
    x[0] = a.x; x[1] = a.y; x[2] = a.z; x[3] = a.w;
    x[4] = b.x; x[5] = b.y; x[6] = b.z; x[7] = b.w;
    x[8] = p[8];
}

// ---- moment accumulators as named floats ----
#define FOR_S(OP) OP(0) OP(1) OP(2) OP(3) OP(4) OP(5) OP(6) OP(7) OP(8)
#define FOR_M(OP) \
    OP(0,0) OP(0,1) OP(0,2) OP(0,3) OP(0,4) OP(0,5) OP(0,6) OP(0,7) OP(0,8) \
    OP(1,1) OP(1,2) OP(1,3) OP(1,4) OP(1,5) OP(1,6) OP(1,7) OP(1,8) \
    OP(2,2) OP(2,3) OP(2,4) OP(2,5) OP(2,6) OP(2,7) OP(2,8) \
    OP(3,3) OP(3,4) OP(3,5) OP(3,6) OP(3,7) OP(3,8) \
    OP(4,4) OP(4,5) OP(4,6) OP(4,7) OP(4,8) \
    OP(5,5) OP(5,6) OP(5,7) OP(5,8) \
    OP(6,6) OP(6,7) OP(6,8) \
    OP(7,7) OP(7,8) \
    OP(8,8)
#define MIDX(k,l) ((k)*NIN - ((k)*((k)-1))/2 + ((l)-(k)))
#define S_DECL(k)   float S_##k = 0.f;
#define M_DECL(k,l) float M_##k##_##l = 0.f;
#define S_ACC(k)    S_##k += x[k];
#define M_ACC(k,l)  M_##k##_##l = fmaf(x[k], x[l], M_##k##_##l);
#define S_RED(k)    S_##k += __shfl_xor(S_##k, off, 64);
#define M_RED(k,l)  M_##k##_##l += __shfl_xor(M_##k##_##l, off, 64);
#define S_ATM(k)    atomicAdd(&red[(k)], S_##k);
#define M_ATM(k,l)  atomicAdd(&red[16 + MIDX(k,l)], M_##k##_##l);

// ---------------- Pass A (FUSED): coarse count+rank (blocks<nbin) + x moments (all) ------------
// Moments phase uses WAVE-PRIVATE LDS STAGING: each wave copies its 64-pt chunk
// (144 float4, 3 fully-coalesced rounds) then reads rows from LDS at dword
// stride 9 (coprime 32 banks -> <=2 lanes/bank = free). Kills the 36B-lane-stride
// global loads (each dwordx4 spanned ~30 cache lines through the L1 tag path).
// Staging applied ONLY here (R5's regression was f1stats' pk/h register pressure;
// this phase has just x[9]+54 accumulators). Numerics bit-identical.
__global__ __launch_bounds__(256, 4) void moments_count_kernel(
    const float* __restrict__ pts, const int* __restrict__ idx,
    float* __restrict__ wsrep, int* __restrict__ rank,
    int* __restrict__ blkcnt, int N, int nb, int nbin)
{
    __shared__ int lhist[NBMAX];
    __shared__ float red[64];
    __shared__ __align__(16) float xstg[4][64 * NIN];
    const int tid = threadIdx.x;
    const int lane = tid & 63, wv = tid >> 6;

    // ---- count phase (block-uniform branch; __syncthreads legal) ----
    if (blockIdx.x < nbin) {
        for (int t = tid; t < nb; t += 256) lhist[t] = 0;
        __syncthreads();
        const int t0 = blockIdx.x * BT_BIN;
#pragma unroll 4
        for (int r = 0; r < BT_BIN / 256; ++r) {
            const int i = t0 + r * 256 + tid;
            if (i < N) rank[i] = atomicAdd(&lhist[idx[i] >> SHIFT], 1);
        }
        __syncthreads();
        for (int t = tid; t < nb; t += 256)
            blkcnt[(size_t)t * nbin + blockIdx.x] = lhist[t];
    }

    // ---- moments phase (all blocks), wave-staged loads ----
    FOR_S(S_DECL)
    FOR_M(M_DECL)

    float* myx = xstg[wv];
    const int nchunks = (N + 63) / 64;
    for (int c = blockIdx.x * 4 + wv; c < nchunks; c += gridDim.x * 4) {
        const int base = c * 64;
        const int npts = min(64, N - base);
        const float* src = pts + (size_t)base * NIN;
        if (npts == 64) {
            const float4* s4 = (const float4*)src;
            float4* m4 = (float4*)myx;
#pragma unroll
            for (int r = 0; r < 3; ++r) {
                const int d = r * 64 + lane;
                if (d < 144) m4[d] = s4[d];   // 64 lanes x 16B = 1KB coalesced
            }
        } else {
            for (int d = lane; d < npts * NIN; d += 64) myx[d] = src[d];
        }
        // same-wave LDS ops are in-order: no barrier needed (verified: R5 run passed)
        if (base + lane < N) {
            float x[NIN];
#pragma unroll
            for (int k = 0; k < NIN; ++k) x[k] = myx[lane * NIN + k];
            FOR_S(S_ACC)
            FOR_M(M_ACC)
        }
    }
#pragma unroll
    for (int off = 32; off > 0; off >>= 1) {
        FOR_S(S_RED)
        FOR_M(M_RED)
    }
    __syncthreads();
    if (tid < 64) red[tid] = 0.f;
    __syncthreads();
    if ((tid & 63) == 0) {
        FOR_S(S_ATM)
        FOR_M(M_ATM)
    }
    __syncthreads();
    if (tid < 64)
        atomicAdd(&wsrep[(blockIdx.x & (NREP - 1)) * 64 + tid], red[tid]);
}

// ---------------- row scan: one block per bucket; row -> relative exclusive bases ----------------
__global__ __launch_bounds__(256) void row_scan_kernel(
    int* __restrict__ blkcnt /* in: counts, out: relative exclusive bases */,
    int* __restrict__ rowsum, int nbin)
{
    __shared__ int part[256];
    int* row = blkcnt + (size_t)blockIdx.x * nbin;
    const int tid = threadIdx.x;
    int carry = 0;
    for (int base = 0; base < nbin; base += 256) {
        const int i = base + tid;
        const int v = (i < nbin) ? row[i] : 0;
        part[tid] = v;
        __syncthreads();
        for (int d = 1; d < 256; d <<= 1) {
            int u = (tid >= d) ? part[tid - d] : 0;
            __syncthreads();
            part[tid] += u;
            __syncthreads();
        }
        const int incl = part[tid];
        const int tot = part[255];
        if (i < nbin) row[i] = carry + incl - v;   // exclusive + carry
        __syncthreads();                           // before next chunk reuses part[]
        carry += tot;
    }
    if (tid == 0) rowsum[blockIdx.x] = carry;
}

// ---------------- offsets scan: 1 block over nb rowsums ----------------
__global__ void offsets_scan_kernel(const int* __restrict__ rowsum,
                                    int* __restrict__ offsets, int nb)
{
    __shared__ int part[1024];
    const int t = threadIdx.x;
    const int v = (t < nb) ? rowsum[t] : 0;
    part[t] = v;
    __syncthreads();
    for (int d = 1; d < 1024; d <<= 1) {
        int u = (t >= d) ? part[t - d] : 0;
        __syncthreads();
        part[t] += u;
        __syncthreads();
    }
    if (t < nb) offsets[t] = part[t] - v;
    if (t == 1023) offsets[nb] = part[1023];
}

// ---------------- finalize1 ----------------
__global__ void finalize1_kernel(
    const float* __restrict__ w1, const float* __restrict__ b1,
    const float* __restrict__ g1, const float* __restrict__ be1,
    const float* __restrict__ wsrep, float* __restrict__ ws, float invN)
{
    __shared__ float sc1s[F1];
    __shared__ float wsl[64];
    const int j = threadIdx.x;
    if (j < 64) {
        float a = 0.f;
#pragma unroll
        for (int r = 0; r < NREP; ++r) a += wsrep[r * 64 + j];
        wsl[j] = a;
    }
    __syncthreads();
    if (j < F1) {
        float W[NIN];
        float P = 0.f;
#pragma unroll
        for (int k = 0; k < NIN; ++k) {
            W[k] = w1[k * F1 + j];
            P = fmaf(wsl[k], W[k], P);
        }
        float Q = 0.f;
        int m = 0;
#pragma unroll
        for (int k = 0; k < NIN; ++k) {
            Q = fmaf(wsl[16 + m], W[k] * W[k], Q); ++m;
#pragma unroll
            for (int l = k + 1; l < NIN; ++l) {
                Q = fmaf(2.f * wsl[16 + m], W[k] * W[l], Q); ++m;
            }
        }
        const float b = b1[j];
        const float mean = fmaf(P, invN, b);
        const float Eh2 = fmaf(fmaf(2.f * b, P, Q), invN, b * b);
        const float var = Eh2 - mean * mean;
        const float sc = g1[j] * rsqrtf(var + EPS);
        ws[WS_SC1 + j] = sc;
        ws[WS_SH1 + j] = be1[j] - mean * sc;
        sc1s[j] = sc;
    }
    __syncthreads();
    for (int m = threadIdx.x; m < NIN * F1; m += blockDim.x)
        ws[WS_W1P + m] = w1[m] * sc1s[m & (F1 - 1)];
}

// f1 (fp32, uniform scalar weights) -> packed bf16 row (32 bf16 = 4 uint4)
__device__ __forceinline__ void f1_row_bf16(
    const float* __restrict__ p, const float* __restrict__ wl,
    const float* __restrict__ sh1, unsigned int* __restrict__ pk /*[16]*/)
{
    float x[NIN];
    load_pt9(p, x);
#pragma unroll
    for (int fc = 0; fc < 4; ++fc) {
        float h[8];
#pragma unroll
        for (int jj = 0; jj < 8; ++jj) h[jj] = sh1[fc * 8 + jj];
#pragma unroll
        for (int k = 0; k < NIN; ++k) {
            const float xv = x[k];
#pragma unroll
            for (int jj = 0; jj < 8; ++jj)
                h[jj] = fmaf(xv, wl[k * F1 + fc * 8 + jj], h[jj]);
        }
#pragma unroll
        for (int jj = 0; jj < 4; ++jj)
            pk[fc * 4 + jj] = pack2(fmaxf(h[2 * jj], 0.f), fmaxf(h[2 * jj + 1], 0.f));
    }
}

// ---------------- MAIN: f1 materialization (sequential) + fused h2 stats ----------------
__global__ __launch_bounds__(256, 3) void f1stats_kernel(
    const float* __restrict__ pts, const float* __restrict__ w2,
    const float* __restrict__ b2, const float* __restrict__ ws,
    float* __restrict__ ws2rep, uint4* __restrict__ f1buf, int N)
{
    __shared__ __align__(16) unsigned char stag[4][64 * ROWB];
    __shared__ float red[2 * F2];

    const int lane = threadIdx.x & 63, wv = threadIdx.x >> 6;
    const int quad = lane >> 4, m16 = lane & 15;

    bf16x8 bfr[4];
#pragma unroll
    for (int nt = 0; nt < 4; ++nt)
#pragma unroll
        for (int j = 0; j < 8; ++j)
            bfr[nt][j] = (short)f2bf(w2[(quad * 8 + j) * F2 + nt * 16 + m16]);
    float b2f[4];
#pragma unroll
    for (int nt = 0; nt < 4; ++nt) b2f[nt] = b2[nt * 16 + m16];

    const float* wl  = ws + WS_W1P;
    const float* sh1 = ws + WS_SH1;
    const f32x4 zero = {0.f, 0.f, 0.f, 0.f};
    float s[4] = {0.f, 0.f, 0.f, 0.f}, ss[4] = {0.f, 0.f, 0.f, 0.f};

    unsigned char* myst = stag[wv];
    const int nchunks = (N + 63) / 64;
    for (int c = blockIdx.x * 4 + wv; c < nchunks; c += gridDim.x * 4) {
        const int i = c * 64 + lane;
        unsigned int pk[16];
        if (i < N) {
            f1_row_bf16(pts + (size_t)i * NIN, wl, sh1, pk);
        } else {
#pragma unroll
            for (int q = 0; q < 16; ++q) pk[q] = 0u;
        }
        uint4* wrow = (uint4*)(myst + lane * ROWB);
#pragma unroll
        for (int cidx = 0; cidx < 4; ++cidx)
            wrow[cidx] = make_uint4(pk[4*cidx+0], pk[4*cidx+1], pk[4*cidx+2], pk[4*cidx+3]);

        if (i < N) {  // sequential 64B row write, in original point order
            uint4* dst = f1buf + (size_t)i * 4;
            dst[0] = make_uint4(pk[0],  pk[1],  pk[2],  pk[3]);
            dst[1] = make_uint4(pk[4],  pk[5],  pk[6],  pk[7]);
            dst[2] = make_uint4(pk[8],  pk[9],  pk[10], pk[11]);
            dst[3] = make_uint4(pk[12], pk[13], pk[14], pk[15]);
        }

        bf16x8 afr[4];
#pragma unroll
        for (int mt = 0; mt < 4; ++mt)
            afr[mt] = *(const bf16x8*)(myst + (mt * 16 + m16) * ROWB + quad * 16);
#pragma unroll
        for (int mt = 0; mt < 4; ++mt) {
#pragma unroll
            for (int nt = 0; nt < 4; ++nt) {
                f32x4 d = __builtin_amdgcn_mfma_f32_16x16x32_bf16(afr[mt], bfr[nt], zero, 0, 0, 0);
#pragma unroll
                for (int rr = 0; rr < 4; ++rr) {
                    const float v = d[rr] + b2f[nt];
                    s[nt] += v;
                    ss[nt] = fmaf(v, v, ss[nt]);
                }
            }
        }
    }

#pragma unroll
    for (int off = 16; off < 64; off <<= 1)
#pragma unroll
        for (int nt = 0; nt < 4; ++nt) {
            s[nt]  += __shfl_xor(s[nt], off, 64);
            ss[nt] += __shfl_xor(ss[nt], off, 64);
        }
    if (threadIdx.x < 2 * F2) red[threadIdx.x] = 0.f;
    __syncthreads();
    if (quad == 0) {
#pragma unroll
        for (int nt = 0; nt < 4; ++nt) {
            atomicAdd(&red[nt * 16 + m16], s[nt]);
            atomicAdd(&red[F2 + nt * 16 + m16], ss[nt]);
        }
    }
    __syncthreads();
    if (threadIdx.x < 2 * F2)
        atomicAdd(&ws2rep[(blockIdx.x & (NREP - 1)) * 128 + threadIdx.x], red[threadIdx.x]);
}

// ---------------- binning: PURE scatter (no histogram, no atomics) ----------------
__global__ __launch_bounds__(256) void binning_kernel(
    const int* __restrict__ idx, const int* __restrict__ rank,
    const int* __restrict__ blkrel, const int* __restrict__ offsets,
    unsigned int* __restrict__ pairpk, int N, int nb, int nbin)
{
    __shared__ int runbase[NBMAX];
    const int tid = threadIdx.x;
    const int b = blockIdx.x;
    const int t0 = b * BT_BIN;
    for (int t = tid; t < nb; t += 256)
        runbase[t] = offsets[t] + blkrel[(size_t)t * nbin + b];
    __syncthreads();
#pragma unroll 4
    for (int r = 0; r < BT_BIN / 256; ++r) {
        const int i = t0 + r * 256 + tid;
        if (i < N) {
            const int sg = idx[i];
            const int p = runbase[sg >> SHIFT] + rank[i];
            pairpk[p] = ((unsigned)i << SHIFT) | (unsigned)(sg & (NSEGB - 1));
        }
    }
}

// ---------------- MAIN: per-bucket window scatter (packed pair, inlined finalize2) ----------------
__global__ __launch_bounds__(256, 3) void bucket_scatter_kernel(
    const uint4* __restrict__ f1buf, const unsigned int* __restrict__ pairpk,
    const float* __restrict__ w2, const float* __restrict__ b2,
    const float* __restrict__ g2, const float* __restrict__ be2,
    const float* __restrict__ ws2rep, const int* __restrict__ offsets,
    unsigned int* __restrict__ out, int nseg, float invN, float padf)
{
    __shared__ unsigned int win[NSEGB * WSTRIDE];
    __shared__ int prl[4][64];

    const int b = blockIdx.x;
    const int start = offsets[b], end = offsets[b + 1];
    const int tid = threadIdx.x;
    const int lane = tid & 63, wv = tid >> 6;
    const int quad = lane >> 4, m16 = lane & 15;

    for (int t = tid; t < NSEGB * WSTRIDE; t += 256) win[t] = 0u;

    bf16x8 bfr[4];
#pragma unroll
    for (int nt = 0; nt < 4; ++nt)
#pragma unroll
        for (int j = 0; j < 8; ++j)
            bfr[nt][j] = (short)f2bf(w2[(quad * 8 + j) * F2 + nt * 16 + m16]);
    float sc2f[4], shb[4];
#pragma unroll
    for (int nt = 0; nt < 4; ++nt) {
        const int f = nt * 16 + m16;
        float S = 0.f, SS = 0.f;
#pragma unroll
        for (int r = 0; r < NREP; ++r) {
            S  += ws2rep[r * 128 + f];
            SS += ws2rep[r * 128 + 64 + f];
        }
        const float bb2 = b2[f];
        S  -= padf * bb2;
        SS -= padf * bb2 * bb2;
        const float mean = S * invN;
        const float var  = SS * invN - mean * mean;
        const float sc   = g2[f] * rsqrtf(var + EPS);
        sc2f[nt] = sc;
        shb[nt]  = fmaf(bb2, sc, be2[f] - mean * sc);
    }
    const f32x4 zero = {0.f, 0.f, 0.f, 0.f};
    __syncthreads();

    const int nch = (end - start + 63) >> 6;
    const bf16x8* fb = (const bf16x8*)f1buf;
    for (int c = wv; c < nch; c += 4) {
        const int cbase = start + c * 64;
        const int sp = cbase + lane;
        int pr = -1;
        if (sp < end) pr = (int)pairpk[sp];
        prl[wv][lane] = pr;

        bf16x8 afr[4];
#pragma unroll
        for (int mt = 0; mt < 4; ++mt) {
            if (cbase + mt * 16 + m16 < end) {
                const unsigned int gi = ((unsigned int)prl[wv][mt * 16 + m16]) >> SHIFT;
                afr[mt] = fb[(size_t)gi * 4 + quad];       // 64B-aligned line-exact gather
            } else {
#pragma unroll
                for (int j = 0; j < 8; ++j) afr[mt][j] = 0;
            }
        }
#pragma unroll
        for (int mt = 0; mt < 4; ++mt) {
            f32x4 d[4];
#pragma unroll
            for (int nt = 0; nt < 4; ++nt)
                d[nt] = __builtin_amdgcn_mfma_f32_16x16x32_bf16(afr[mt], bfr[nt], zero, 0, 0, 0);
#pragma unroll
            for (int rr = 0; rr < 4; ++rr) {
                const int v = prl[wv][mt * 16 + quad * 4 + rr];
                if (v >= 0) {
                    const int sl = v & (NSEGB - 1);
#pragma unroll
                    for (int nt = 0; nt < 4; ++nt) {
                        const float vv = fmaf(d[nt][rr], sc2f[nt], shb[nt]);
                        if (vv > 0.f)
                            atomicMax(&win[sl * WSTRIDE + nt * 16 + m16], __float_as_uint(vv));
                    }
                }
            }
        }
    }
    __syncthreads();
    const int segbase = b << SHIFT;
    const int rows = min(NSEGB, nseg - segbase);
    for (int t = tid; t < rows * 64; t += 256)
        out[(size_t)(segbase + (t >> 6)) * 64 + (t & 63)] = win[(t >> 6) * WSTRIDE + (t & 63)];
}

// ---------------- FALLBACK: standalone h2 stats (no f1buf) ----------------
__global__ __launch_bounds__(256, 3) void stats2_kernel(
    const float* __restrict__ pts, const float* __restrict__ w2,
    const float* __restrict__ b2, const float* __restrict__ ws,
    float* __restrict__ ws2rep, int N)
{
    __shared__ __align__(16) unsigned char stag[4][64 * ROWB];
    __shared__ float red[2 * F2];

    const int lane = threadIdx.x & 63, wv = threadIdx.x >> 6;
    const int quad = lane >> 4, m16 = lane & 15;

    bf16x8 bfr[4];
#pragma unroll
    for (int nt = 0; nt < 4; ++nt)
#pragma unroll
        for (int j = 0; j < 8; ++j)
            bfr[nt][j] = (short)f2bf(w2[(quad * 8 + j) * F2 + nt * 16 + m16]);
    float b2f[4];
#pragma unroll
    for (int nt = 0; nt < 4; ++nt) b2f[nt] = b2[nt * 16 + m16];

    const float* wl  = ws + WS_W1P;
    const float* sh1 = ws + WS_SH1;
    const f32x4 zero = {0.f, 0.f, 0.f, 0.f};
    float s[4] = {0.f, 0.f, 0.f, 0.f}, ss[4] = {0.f, 0.f, 0.f, 0.f};

    unsigned char* myst = stag[wv];
    const int nchunks = (N + 63) / 64;
    for (int c = blockIdx.x * 4 + wv; c < nchunks; c += gridDim.x * 4) {
        const int i = c * 64 + lane;
        unsigned int pk[16];
        if (i < N) {
            f1_row_bf16(pts + (size_t)i * NIN, wl, sh1, pk);
        } else {
#pragma unroll
            for (int q = 0; q < 16; ++q) pk[q] = 0u;
        }
        uint4* wrow = (uint4*)(myst + lane * ROWB);
#pragma unroll
        for (int cidx = 0; cidx < 4; ++cidx)
            wrow[cidx] = make_uint4(pk[4*cidx+0], pk[4*cidx+1], pk[4*cidx+2], pk[4*cidx+3]);

        bf16x8 afr[4];
#pragma unroll
        for (int mt = 0; mt < 4; ++mt)
            afr[mt] = *(const bf16x8*)(myst + (mt * 16 + m16) * ROWB + quad * 16);
#pragma unroll
        for (int mt = 0; mt < 4; ++mt) {
#pragma unroll
            for (int nt = 0; nt < 4; ++nt) {
                f32x4 d = __builtin_amdgcn_mfma_f32_16x16x32_bf16(afr[mt], bfr[nt], zero, 0, 0, 0);
#pragma unroll
                for (int rr = 0; rr < 4; ++rr) {
                    const float v = d[rr] + b2f[nt];
                    s[nt] += v;
                    ss[nt] = fmaf(v, v, ss[nt]);
                }
            }
        }
    }
#pragma unroll
    for (int off = 16; off < 64; off <<= 1)
#pragma unroll
        for (int nt = 0; nt < 4; ++nt) {
            s[nt]  += __shfl_xor(s[nt], off, 64);
            ss[nt] += __shfl_xor(ss[nt], off, 64);
        }
    if (threadIdx.x < 2 * F2) red[threadIdx.x] = 0.f;
    __syncthreads();
    if (quad == 0) {
#pragma unroll
        for (int nt = 0; nt < 4; ++nt) {
            atomicAdd(&red[nt * 16 + m16], s[nt]);
            atomicAdd(&red[F2 + nt * 16 + m16], ss[nt]);
        }
    }
    __syncthreads();
    if (threadIdx.x < 2 * F2)
        atomicAdd(&ws2rep[(blockIdx.x & (NREP - 1)) * 128 + threadIdx.x], red[threadIdx.x]);
}

// ---------------- FALLBACK: per-bucket window scatter, recomputing f1 from pts ----------------
__global__ __launch_bounds__(256, 2) void bucket_scatter_gather_kernel(
    const float* __restrict__ pts, const unsigned int* __restrict__ pairpk,
    const float* __restrict__ w2, const float* __restrict__ b2,
    const float* __restrict__ g2, const float* __restrict__ be2,
    const float* __restrict__ ws, const float* __restrict__ ws2rep,
    const int* __restrict__ offsets,
    unsigned int* __restrict__ out, int nseg, float invN, float padf)
{
    __shared__ unsigned int win[NSEGB * WSTRIDE];
    __shared__ __align__(16) unsigned char stag[4][64 * ROWB];
    __shared__ int segl[4][64];

    const int b = blockIdx.x;
    const int start = offsets[b], end = offsets[b + 1];
    const int tid = threadIdx.x;
    const int lane = tid & 63, wv = tid >> 6;
    const int quad = lane >> 4, m16 = lane & 15;

    for (int t = tid; t < NSEGB * WSTRIDE; t += 256) win[t] = 0u;

    bf16x8 bfr[4];
#pragma unroll
    for (int nt = 0; nt < 4; ++nt)
#pragma unroll
        for (int j = 0; j < 8; ++j)
            bfr[nt][j] = (short)f2bf(w2[(quad * 8 + j) * F2 + nt * 16 + m16]);
    float sc2f[4], shb[4];
#pragma unroll
    for (int nt = 0; nt < 4; ++nt) {
        const int f = nt * 16 + m16;
        float S = 0.f, SS = 0.f;
#pragma unroll
        for (int r = 0; r < NREP; ++r) {
            S  += ws2rep[r * 128 + f];
            SS += ws2rep[r * 128 + 64 + f];
        }
        const float bb2 = b2[f];
        S  -= padf * bb2;
        SS -= padf * bb2 * bb2;
        const float mean = S * invN;
        const float var  = SS * invN - mean * mean;
        const float sc   = g2[f] * rsqrtf(var + EPS);
        sc2f[nt] = sc;
        shb[nt]  = fmaf(bb2, sc, be2[f] - mean * sc);
    }
    const float* wl  = ws + WS_W1P;
    const float* sh1 = ws + WS_SH1;
    const f32x4 zero = {0.f, 0.f, 0.f, 0.f};
    __syncthreads();

    const int nch = (end - start + 63) >> 6;
    unsigned char* myst = stag[wv];
    for (int c = wv; c < nch; c += 4) {
        const int cbase = start + c * 64;
        const int sp = cbase + lane;
        unsigned int pk[16];
        int sl = -1;
        if (sp < end) {
            const unsigned int v = pairpk[sp];
            f1_row_bf16(pts + (size_t)(v >> SHIFT) * NIN, wl, sh1, pk);
            sl = (int)(v & (NSEGB - 1));
        } else {
#pragma unroll
            for (int q = 0; q < 16; ++q) pk[q] = 0u;
        }
        segl[wv][lane] = sl;
        uint4* wrow = (uint4*)(myst + lane * ROWB);
#pragma unroll
        for (int cidx = 0; cidx < 4; ++cidx)
            wrow[cidx] = make_uint4(pk[4*cidx+0], pk[4*cidx+1], pk[4*cidx+2], pk[4*cidx+3]);

        bf16x8 afr[4];
#pragma unroll
        for (int mt = 0; mt < 4; ++mt)
            afr[mt] = *(const bf16x8*)(myst + (mt * 16 + m16) * ROWB + quad * 16);
#pragma unroll
        for (int mt = 0; mt < 4; ++mt) {
            f32x4 d[4];
#pragma unroll
            for (int nt = 0; nt < 4; ++nt)
                d[nt] = __builtin_amdgcn_mfma_f32_16x16x32_bf16(afr[mt], bfr[nt], zero, 0, 0, 0);
#pragma unroll
            for (int rr = 0; rr < 4; ++rr) {
                const int sl2 = segl[wv][mt * 16 + quad * 4 + rr];
                if (sl2 >= 0) {
#pragma unroll
                    for (int nt = 0; nt < 4; ++nt) {
                        const float vv = fmaf(d[nt][rr], sc2f[nt], shb[nt]);
                        if (vv > 0.f)
                            atomicMax(&win[sl2 * WSTRIDE + nt * 16 + m16], __float_as_uint(vv));
                    }
                }
            }
        }
    }
    __syncthreads();
    const int segbase = b << SHIFT;
    const int rows = min(NSEGB, nseg - segbase);
    for (int t = tid; t < rows * 64; t += 256)
        out[(size_t)(segbase + (t >> 6)) * 64 + (t & 63)] = win[(t >> 6) * WSTRIDE + (t & 63)];
}

extern "C" void kernel_launch(void* const* d_in, const int* in_sizes, int n_in,
                              void* d_out, int out_size, void* d_ws, size_t ws_size,
                              hipStream_t stream)
{
    const float* pts = (const float*)d_in[0];
    const int*   idx = (const int*)d_in[1];
    const float* w1  = (const float*)d_in[3];
    const float* b1  = (const float*)d_in[4];
    const float* g1  = (const float*)d_in[5];
    const float* be1 = (const float*)d_in[6];
    const float* w2  = (const float*)d_in[7];
    const float* b2  = (const float*)d_in[8];
    const float* g2  = (const float*)d_in[9];
    const float* be2 = (const float*)d_in[10];

    const int N = in_sizes[0] / NIN;
    const int nseg = out_size / F2;
    int nb = (nseg + NSEGB - 1) >> SHIFT;
    if (nb > NBMAX) nb = NBMAX;
    const int nbin = (N + BT_BIN - 1) / BT_BIN;
    const float invN = 1.0f / (float)N;
    const float padf = (float)((64 - (N & 63)) & 63);

    char* base = (char*)d_ws;
    const size_t f1bytes   = (size_t)N * 64;
    const size_t pairbytes = (size_t)N * 4;   // packed (i<<SHIFT)|sl
    const size_t rankbytes = (size_t)N * 4;
    const size_t repbytes  = (size_t)NREP * 192 * 4;           // wsrep(64)+ws2rep(128)
    const size_t blkbytes  = (size_t)nb * nbin * 4;
    const size_t tailbytes = 4096 + repbytes + blkbytes +
                             ((size_t)NBMAX + 1 + NBMAX) * 4 + 256;
    const size_t need_main = f1bytes + pairbytes + rankbytes + tailbytes;

    // fused pass A grid: >= nbin so every count slice is covered; 1024 = 4 blocks/CU
    int gA = 1024;
    if (gA < nbin) gA = nbin;

    if (ws_size >= need_main) {
        // ---- main path ----
        uint4*        f1buf   = (uint4*)base;
        unsigned int* pairpk  = (unsigned int*)(base + f1bytes);
        int*          rank    = (int*)(base + f1bytes + pairbytes);
        char*         tail    = base + f1bytes + pairbytes + rankbytes;
        float*        ws      = (float*)tail;
        float*        wsrep   = (float*)(tail + 4096);
        float*        ws2rep  = wsrep + NREP * 64;
        int*          blkcnt  = (int*)(tail + 4096 + repbytes);
        int*          rowsum  = (int*)(tail + 4096 + repbytes + blkbytes);
        int*          offsets = rowsum + NBMAX;

        hipMemsetAsync(wsrep, 0, repbytes, stream);

        moments_count_kernel<<<gA, 256, 0, stream>>>(pts, idx, wsrep, rank, blkcnt, N, nb, nbin);
        finalize1_kernel<<<1, 320, 0, stream>>>(w1, b1, g1, be1, wsrep, ws, invN);
        row_scan_kernel<<<nb, 256, 0, stream>>>(blkcnt, rowsum, nbin);
        offsets_scan_kernel<<<1, 1024, 0, stream>>>(rowsum, offsets, nb);
        f1stats_kernel<<<1536, 256, 0, stream>>>(pts, w2, b2, ws, ws2rep, f1buf, N);
        binning_kernel<<<nbin, 256, 0, stream>>>(idx, rank, blkcnt, offsets, pairpk, N, nb, nbin);
        bucket_scatter_kernel<<<nb, 256, 0, stream>>>(
            f1buf, pairpk, w2, b2, g2, be2, ws2rep, offsets,
            (unsigned int*)d_out, nseg, invN, padf);
    } else {
        // ---- fallback: no f1 materialization ----
        unsigned int* pairpk  = (unsigned int*)base;
        int*          rank    = (int*)(base + pairbytes);
        char*         tail    = base + pairbytes + rankbytes;
        float*        ws      = (float*)tail;
        float*        wsrep   = (float*)(tail + 4096);
        float*        ws2rep  = wsrep + NREP * 64;
        int*          blkcnt  = (int*)(tail + 4096 + repbytes);
        int*          rowsum  = (int*)(tail + 4096 + repbytes + blkbytes);
        int*          offsets = rowsum + NBMAX;

        hipMemsetAsync(wsrep, 0, repbytes, stream);

        moments_count_kernel<<<gA, 256, 0, stream>>>(pts, idx, wsrep, rank, blkcnt, N, nb, nbin);
        finalize1_kernel<<<1, 320, 0, stream>>>(w1, b1, g1, be1, wsrep, ws, invN);
        row_scan_kernel<<<nb, 256, 0, stream>>>(blkcnt, rowsum, nbin);
        offsets_scan_kernel<<<1, 1024, 0, stream>>>(rowsum, offsets, nb);
        binning_kernel<<<nbin, 256, 0, stream>>>(idx, rank, blkcnt, offsets, pairpk, N, nb, nbin);
        stats2_kernel<<<1024, 256, 0, stream>>>(pts, w2, b2, ws, ws2rep, N);
        bucket_scatter_gather_kernel<<<nb, 256, 0, stream>>>(
            pts, pairpk, w2, b2, g2, be2, ws, ws2rep, offsets,
            (unsigned int*)d_out, nseg, invN, padf);
    }
}

// Round 13
// 282.358 us; speedup vs baseline: 1.0231x; 1.0231x over previous
//
#include <hip/hip_runtime.h>

#define EPS 1e-5f
#define NIN 9
#define F1 32
#define F2 64
#define ROWB 80       // bytes per bf16 f1 row in LDS staging
#define SHIFT 7       // coarse bucket = seg >> 7 (128 segs/bucket)
#define NSEGB 128     // segs per bucket
#define NBMAX 1024
#define BT_BIN 4096   // points per count/binning slice
#define WSTRIDE 68    // dwords per window row (padded)
#define NREP 32       // atomic-target replicas

// params region float offsets (ws)
#define WS_SC1  192
#define WS_SH1  224
#define WS_W1P  256

typedef __attribute__((ext_vector_type(8))) short bf16x8;
typedef __attribute__((ext_vector_type(4))) float f32x4;

__device__ __forceinline__ unsigned int f2bf(float f) {
    unsigned int u = __float_as_uint(f);
    return (u + 0x7fffu + ((u >> 16) & 1u)) >> 16;   // RNE
}
__device__ __forceinline__ unsigned int pack2(float lo, float hi) {
    unsigned int r;
    asm("v_cvt_pk_bf16_f32 %0, %1, %2" : "=v"(r) : "v"(lo), "v"(hi));
    return r;
}

// 9-float point row in 3 vmem instructions (2x dwordx4 + 1 dword)
__device__ __forceinline__ void load_pt9(const float* __restrict__ p, float* __restrict__ x)
{
    const float4* p4 = (const float4*)p;
    const float4 a = p4[0];
    const float4 b = p4[1];
    x[0] = a.x; x[1] = a.y; x[2] = a.z; x[3] = a.w;
    x[4] = b.x; x[5] = b.y; x[6] = b.z; x[7] = b.w;
    x[8] = p[8];
}

// ---- moment accumulators as named floats ----
#define FOR_S(OP) OP(0) OP(1) OP(2) OP(3) OP(4) OP(5) OP(6) OP(7) OP(8)
#define FOR_M(OP) \
    OP(0,0) OP(0,1) OP(0,2) OP(0,3) OP(0,4) OP(0,5) OP(0,6) OP(0,7) OP(0,8) \
    OP(1,1) OP(1,2) OP(1,3) OP(1,4) OP(1,5) OP(1,6) OP(1,7) OP(1,8) \
    OP(2,2) OP(2,3) OP(2,4) OP(2,5) OP(2,6) OP(2,7) OP(2,8) \
    OP(3,3) OP(3,4) OP(3,5) OP(3,6) OP(3,7) OP(3,8) \
    OP(4,4) OP(4,5) OP(4,6) OP(4,7) OP(4,8) \
    OP(5,5) OP(5,6) OP(5,7) OP(5,8) \
    OP(6,6) OP(6,7) OP(6,8) \
    OP(7,7) OP(7,8) \
    OP(8,8)
#define MIDX(k,l) ((k)*NIN - ((k)*((k)-1))/2 + ((l)-(k)))
#define S_DECL(k)   float S_##k = 0.f;
#define M_DECL(k,l) float M_##k##_##l = 0.f;
#define S_ACC(k)    S_##k += x[k];
#define M_ACC(k,l)  M_##k##_##l = fmaf(x[k], x[l], M_##k##_##l);
#define S_RED(k)    S_##k += __shfl_xor(S_##k, off, 64);
#define M_RED(k,l)  M_##k##_##l += __shfl_xor(M_##k##_##l, off, 64);
#define S_ATM(k)    atomicAdd(&red[(k)], S_##k);
#define M_ATM(k,l)  atomicAdd(&red[16 + MIDX(k,l)], M_##k##_##l);

// ---------------- Pass A (FUSED): coarse count+rank (blocks<nbin) + x moments (all) ------------
// (R11 form: plain grid-stride loads — 5 body variants all measured equal; simplest kept.)
__global__ __launch_bounds__(256, 4) void moments_count_kernel(
    const float* __restrict__ pts, const int* __restrict__ idx,
    float* __restrict__ wsrep, int* __restrict__ rank,
    int* __restrict__ blkcnt, int N, int nb, int nbin)
{
    __shared__ int lhist[NBMAX];
    __shared__ float red[64];
    const int tid = threadIdx.x;

    // ---- count phase (block-uniform branch; __syncthreads legal) ----
    if (blockIdx.x < nbin) {
        for (int t = tid; t < nb; t += 256) lhist[t] = 0;
        __syncthreads();
        const int t0 = blockIdx.x * BT_BIN;
#pragma unroll 4
        for (int r = 0; r < BT_BIN / 256; ++r) {
            const int i = t0 + r * 256 + tid;
            if (i < N) rank[i] = atomicAdd(&lhist[idx[i] >> SHIFT], 1);
        }
        __syncthreads();
        for (int t = tid; t < nb; t += 256)
            blkcnt[(size_t)t * nbin + blockIdx.x] = lhist[t];
    }

    // ---- moments phase (all blocks) ----
    FOR_S(S_DECL)
    FOR_M(M_DECL)

    const int stride = gridDim.x * blockDim.x;
    for (int i = blockIdx.x * blockDim.x + tid; i < N; i += stride) {
        float x[NIN];
        load_pt9(pts + (size_t)i * NIN, x);
        FOR_S(S_ACC)
        FOR_M(M_ACC)
    }
#pragma unroll
    for (int off = 32; off > 0; off >>= 1) {
        FOR_S(S_RED)
        FOR_M(M_RED)
    }
    __syncthreads();
    if (tid < 64) red[tid] = 0.f;
    __syncthreads();
    if ((tid & 63) == 0) {
        FOR_S(S_ATM)
        FOR_M(M_ATM)
    }
    __syncthreads();
    if (tid < 64)
        atomicAdd(&wsrep[(blockIdx.x & (NREP - 1)) * 64 + tid], red[tid]);
}

// ---------------- FUSED: block 0 = finalize1; blocks 1..nb = row scan ----------------
__global__ __launch_bounds__(256) void scan_finalize1_kernel(
    const float* __restrict__ w1, const float* __restrict__ b1,
    const float* __restrict__ g1, const float* __restrict__ be1,
    const float* __restrict__ wsrep, float* __restrict__ ws, float invN,
    int* __restrict__ blkcnt /* in: counts, out: relative exclusive bases */,
    int* __restrict__ rowsum, int nbin)
{
    const int tid = threadIdx.x;
    if (blockIdx.x == 0) {
        // ---- finalize1 (layer-1 BN affine + scaled W1) ----
        __shared__ float sc1s[F1];
        __shared__ float wsl[64];
        if (tid < 64) {
            float a = 0.f;
#pragma unroll
            for (int r = 0; r < NREP; ++r) a += wsrep[r * 64 + tid];
            wsl[tid] = a;
        }
        __syncthreads();
        if (tid < F1) {
            float W[NIN];
            float P = 0.f;
#pragma unroll
            for (int k = 0; k < NIN; ++k) {
                W[k] = w1[k * F1 + tid];
                P = fmaf(wsl[k], W[k], P);
            }
            float Q = 0.f;
            int m = 0;
#pragma unroll
            for (int k = 0; k < NIN; ++k) {
                Q = fmaf(wsl[16 + m], W[k] * W[k], Q); ++m;
#pragma unroll
                for (int l = k + 1; l < NIN; ++l) {
                    Q = fmaf(2.f * wsl[16 + m], W[k] * W[l], Q); ++m;
                }
            }
            const float b = b1[tid];
            const float mean = fmaf(P, invN, b);
            const float Eh2 = fmaf(fmaf(2.f * b, P, Q), invN, b * b);
            const float var = Eh2 - mean * mean;
            const float sc = g1[tid] * rsqrtf(var + EPS);
            ws[WS_SC1 + tid] = sc;
            ws[WS_SH1 + tid] = be1[tid] - mean * sc;
            sc1s[tid] = sc;
        }
        __syncthreads();
        for (int m = tid; m < NIN * F1; m += 256)
            ws[WS_W1P + m] = w1[m] * sc1s[m & (F1 - 1)];
        return;
    }
    // ---- row scan for bucket (blockIdx.x - 1) ----
    __shared__ int part[256];
    int* row = blkcnt + (size_t)(blockIdx.x - 1) * nbin;
    int carry = 0;
    for (int base = 0; base < nbin; base += 256) {
        const int i = base + tid;
        const int v = (i < nbin) ? row[i] : 0;
        part[tid] = v;
        __syncthreads();
        for (int d = 1; d < 256; d <<= 1) {
            int u = (tid >= d) ? part[tid - d] : 0;
            __syncthreads();
            part[tid] += u;
            __syncthreads();
        }
        const int incl = part[tid];
        const int tot = part[255];
        if (i < nbin) row[i] = carry + incl - v;   // exclusive + carry
        __syncthreads();                           // before next chunk reuses part[]
        carry += tot;
    }
    if (tid == 0) rowsum[blockIdx.x - 1] = carry;
}

// ---------------- offsets scan: 1 block over nb rowsums ----------------
__global__ void offsets_scan_kernel(const int* __restrict__ rowsum,
                                    int* __restrict__ offsets, int nb)
{
    __shared__ int part[1024];
    const int t = threadIdx.x;
    const int v = (t < nb) ? rowsum[t] : 0;
    part[t] = v;
    __syncthreads();
    for (int d = 1; d < 1024; d <<= 1) {
        int u = (t >= d) ? part[t - d] : 0;
        __syncthreads();
        part[t] += u;
        __syncthreads();
    }
    if (t < nb) offsets[t] = part[t] - v;
    if (t == 1023) offsets[nb] = part[1023];
}

// f1 (fp32, uniform scalar weights) -> packed bf16 row (32 bf16 = 4 uint4)
__device__ __forceinline__ void f1_row_bf16(
    const float* __restrict__ p, const float* __restrict__ wl,
    const float* __restrict__ sh1, unsigned int* __restrict__ pk /*[16]*/)
{
    float x[NIN];
    load_pt9(p, x);
#pragma unroll
    for (int fc = 0; fc < 4; ++fc) {
        float h[8];
#pragma unroll
        for (int jj = 0; jj < 8; ++jj) h[jj] = sh1[fc * 8 + jj];
#pragma unroll
        for (int k = 0; k < NIN; ++k) {
            const float xv = x[k];
#pragma unroll
            for (int jj = 0; jj < 8; ++jj)
                h[jj] = fmaf(xv, wl[k * F1 + fc * 8 + jj], h[jj]);
        }
#pragma unroll
        for (int jj = 0; jj < 4; ++jj)
            pk[fc * 4 + jj] = pack2(fmaxf(h[2 * jj], 0.f), fmaxf(h[2 * jj + 1], 0.f));
    }
}

// ---------------- MAIN: f1 materialization + fused RAW h2 stats ----------------
// Accumulates raw a = (f1 . w2col) sums (no +b2): variance is translation-
// invariant, b2 cancels in the output affine, padded zero rows contribute 0.
// Removes 1/3 of the epilogue VALU and the padf correction entirely.
__global__ __launch_bounds__(256, 3) void f1stats_kernel(
    const float* __restrict__ pts, const float* __restrict__ w2,
    const float* __restrict__ ws, float* __restrict__ ws2rep,
    uint4* __restrict__ f1buf, int N)
{
    __shared__ __align__(16) unsigned char stag[4][64 * ROWB];
    __shared__ float red[2 * F2];

    const int lane = threadIdx.x & 63, wv = threadIdx.x >> 6;
    const int quad = lane >> 4, m16 = lane & 15;

    bf16x8 bfr[4];
#pragma unroll
    for (int nt = 0; nt < 4; ++nt)
#pragma unroll
        for (int j = 0; j < 8; ++j)
            bfr[nt][j] = (short)f2bf(w2[(quad * 8 + j) * F2 + nt * 16 + m16]);

    const float* wl  = ws + WS_W1P;
    const float* sh1 = ws + WS_SH1;
    const f32x4 zero = {0.f, 0.f, 0.f, 0.f};
    float s[4] = {0.f, 0.f, 0.f, 0.f}, ss[4] = {0.f, 0.f, 0.f, 0.f};

    unsigned char* myst = stag[wv];
    const int nchunks = (N + 63) / 64;
    for (int c = blockIdx.x * 4 + wv; c < nchunks; c += gridDim.x * 4) {
        const int i = c * 64 + lane;
        unsigned int pk[16];
        if (i < N) {
            f1_row_bf16(pts + (size_t)i * NIN, wl, sh1, pk);
        } else {
#pragma unroll
            for (int q = 0; q < 16; ++q) pk[q] = 0u;
        }
        uint4* wrow = (uint4*)(myst + lane * ROWB);
#pragma unroll
        for (int cidx = 0; cidx < 4; ++cidx)
            wrow[cidx] = make_uint4(pk[4*cidx+0], pk[4*cidx+1], pk[4*cidx+2], pk[4*cidx+3]);

        if (i < N) {  // sequential 64B row write, in original point order
            uint4* dst = f1buf + (size_t)i * 4;
            dst[0] = make_uint4(pk[0],  pk[1],  pk[2],  pk[3]);
            dst[1] = make_uint4(pk[4],  pk[5],  pk[6],  pk[7]);
            dst[2] = make_uint4(pk[8],  pk[9],  pk[10], pk[11]);
            dst[3] = make_uint4(pk[12], pk[13], pk[14], pk[15]);
        }

        bf16x8 afr[4];
#pragma unroll
        for (int mt = 0; mt < 4; ++mt)
            afr[mt] = *(const bf16x8*)(myst + (mt * 16 + m16) * ROWB + quad * 16);
#pragma unroll
        for (int mt = 0; mt < 4; ++mt) {
#pragma unroll
            for (int nt = 0; nt < 4; ++nt) {
                f32x4 d = __builtin_amdgcn_mfma_f32_16x16x32_bf16(afr[mt], bfr[nt], zero, 0, 0, 0);
#pragma unroll
                for (int rr = 0; rr < 4; ++rr) {
                    const float a = d[rr];
                    s[nt] += a;
                    ss[nt] = fmaf(a, a, ss[nt]);
                }
            }
        }
    }

#pragma unroll
    for (int off = 16; off < 64; off <<= 1)
#pragma unroll
        for (int nt = 0; nt < 4; ++nt) {
            s[nt]  += __shfl_xor(s[nt], off, 64);
            ss[nt] += __shfl_xor(ss[nt], off, 64);
        }
    if (threadIdx.x < 2 * F2) red[threadIdx.x] = 0.f;
    __syncthreads();
    if (quad == 0) {
#pragma unroll
        for (int nt = 0; nt < 4; ++nt) {
            atomicAdd(&red[nt * 16 + m16], s[nt]);
            atomicAdd(&red[F2 + nt * 16 + m16], ss[nt]);
        }
    }
    __syncthreads();
    if (threadIdx.x < 2 * F2)
        atomicAdd(&ws2rep[(blockIdx.x & (NREP - 1)) * 128 + threadIdx.x], red[threadIdx.x]);
}

// ---------------- binning: PURE scatter (no histogram, no atomics) ----------------
__global__ __launch_bounds__(256) void binning_kernel(
    const int* __restrict__ idx, const int* __restrict__ rank,
    const int* __restrict__ blkrel, const int* __restrict__ offsets,
    unsigned int* __restrict__ pairpk, int N, int nb, int nbin)
{
    __shared__ int runbase[NBMAX];
    const int tid = threadIdx.x;
    const int b = blockIdx.x;
    const int t0 = b * BT_BIN;
    for (int t = tid; t < nb; t += 256)
        runbase[t] = offsets[t] + blkrel[(size_t)t * nbin + b];
    __syncthreads();
#pragma unroll 4
    for (int r = 0; r < BT_BIN / 256; ++r) {
        const int i = t0 + r * 256 + tid;
        if (i < N) {
            const int sg = idx[i];
            const int p = runbase[sg >> SHIFT] + rank[i];
            pairpk[p] = ((unsigned)i << SHIFT) | (unsigned)(sg & (NSEGB - 1));
        }
    }
}

// ---------------- MAIN: per-bucket window scatter (raw-stat finalize2 inlined) ----------------
// mean_a = S/N; var = SS/N - mean_a^2 (translation-invariant, b2 cancels):
// out = a*sc + (be2 - mean_a*sc).
__global__ __launch_bounds__(256, 3) void bucket_scatter_kernel(
    const uint4* __restrict__ f1buf, const unsigned int* __restrict__ pairpk,
    const float* __restrict__ w2,
    const float* __restrict__ g2, const float* __restrict__ be2,
    const float* __restrict__ ws2rep, const int* __restrict__ offsets,
    unsigned int* __restrict__ out, int nseg, float invN)
{
    __shared__ unsigned int win[NSEGB * WSTRIDE];
    __shared__ int prl[4][64];

    const int b = blockIdx.x;
    const int start = offsets[b], end = offsets[b + 1];
    const int tid = threadIdx.x;
    const int lane = tid & 63, wv = tid >> 6;
    const int quad = lane >> 4, m16 = lane & 15;

    for (int t = tid; t < NSEGB * WSTRIDE; t += 256) win[t] = 0u;

    bf16x8 bfr[4];
#pragma unroll
    for (int nt = 0; nt < 4; ++nt)
#pragma unroll
        for (int j = 0; j < 8; ++j)
            bfr[nt][j] = (short)f2bf(w2[(quad * 8 + j) * F2 + nt * 16 + m16]);
    float sc2f[4], shb[4];
#pragma unroll
    for (int nt = 0; nt < 4; ++nt) {
        const int f = nt * 16 + m16;
        float S = 0.f, SS = 0.f;
#pragma unroll
        for (int r = 0; r < NREP; ++r) {
            S  += ws2rep[r * 128 + f];
            SS += ws2rep[r * 128 + 64 + f];
        }
        const float mean_a = S * invN;
        const float var    = SS * invN - mean_a * mean_a;
        const float sc     = g2[f] * rsqrtf(var + EPS);
        sc2f[nt] = sc;
        shb[nt]  = be2[f] - mean_a * sc;
    }
    const f32x4 zero = {0.f, 0.f, 0.f, 0.f};
    __syncthreads();

    const int nch = (end - start + 63) >> 6;
    const bf16x8* fb = (const bf16x8*)f1buf;
    for (int c = wv; c < nch; c += 4) {
        const int cbase = start + c * 64;
        const int sp = cbase + lane;
        int pr = -1;
        if (sp < end) pr = (int)pairpk[sp];
        prl[wv][lane] = pr;

        bf16x8 afr[4];
#pragma unroll
        for (int mt = 0; mt < 4; ++mt) {
            if (cbase + mt * 16 + m16 < end) {
                const unsigned int gi = ((unsigned int)prl[wv][mt * 16 + m16]) >> SHIFT;
                afr[mt] = fb[(size_t)gi * 4 + quad];       // 64B-aligned line-exact gather
            } else {
#pragma unroll
                for (int j = 0; j < 8; ++j) afr[mt][j] = 0;
            }
        }
#pragma unroll
        for (int mt = 0; mt < 4; ++mt) {
            f32x4 d[4];
#pragma unroll
            for (int nt = 0; nt < 4; ++nt)
                d[nt] = __builtin_amdgcn_mfma_f32_16x16x32_bf16(afr[mt], bfr[nt], zero, 0, 0, 0);
#pragma unroll
            for (int rr = 0; rr < 4; ++rr) {
                const int v = prl[wv][mt * 16 + quad * 4 + rr];
                if (v >= 0) {
                    const int sl = v & (NSEGB - 1);
#pragma unroll
                    for (int nt = 0; nt < 4; ++nt) {
                        const float vv = fmaf(d[nt][rr], sc2f[nt], shb[nt]);
                        if (vv > 0.f)
                            atomicMax(&win[sl * WSTRIDE + nt * 16 + m16], __float_as_uint(vv));
                    }
                }
            }
        }
    }
    __syncthreads();
    const int segbase = b << SHIFT;
    const int rows = min(NSEGB, nseg - segbase);
    for (int t = tid; t < rows * 64; t += 256)
        out[(size_t)(segbase + (t >> 6)) * 64 + (t & 63)] = win[(t >> 6) * WSTRIDE + (t & 63)];
}

// ---------------- FALLBACK: standalone raw h2 stats (no f1buf) ----------------
__global__ __launch_bounds__(256, 3) void stats2_kernel(
    const float* __restrict__ pts, const float* __restrict__ w2,
    const float* __restrict__ ws, float* __restrict__ ws2rep, int N)
{
    __shared__ __align__(16) unsigned char stag[4][64 * ROWB];
    __shared__ float red[2 * F2];

    const int lane = threadIdx.x & 63, wv = threadIdx.x >> 6;
    const int quad = lane >> 4, m16 = lane & 15;

    bf16x8 bfr[4];
#pragma unroll
    for (int nt = 0; nt < 4; ++nt)
#pragma unroll
        for (int j = 0; j < 8; ++j)
            bfr[nt][j] = (short)f2bf(w2[(quad * 8 + j) * F2 + nt * 16 + m16]);

    const float* wl  = ws + WS_W1P;
    const float* sh1 = ws + WS_SH1;
    const f32x4 zero = {0.f, 0.f, 0.f, 0.f};
    float s[4] = {0.f, 0.f, 0.f, 0.f}, ss[4] = {0.f, 0.f, 0.f, 0.f};

    unsigned char* myst = stag[wv];
    const int nchunks = (N + 63) / 64;
    for (int c = blockIdx.x * 4 + wv; c < nchunks; c += gridDim.x * 4) {
        const int i = c * 64 + lane;
        unsigned int pk[16];
        if (i < N) {
            f1_row_bf16(pts + (size_t)i * NIN, wl, sh1, pk);
        } else {
#pragma unroll
            for (int q = 0; q < 16; ++q) pk[q] = 0u;
        }
        uint4* wrow = (uint4*)(myst + lane * ROWB);
#pragma unroll
        for (int cidx = 0; cidx < 4; ++cidx)
            wrow[cidx] = make_uint4(pk[4*cidx+0], pk[4*cidx+1], pk[4*cidx+2], pk[4*cidx+3]);

        bf16x8 afr[4];
#pragma unroll
        for (int mt = 0; mt < 4; ++mt)
            afr[mt] = *(const bf16x8*)(myst + (mt * 16 + m16) * ROWB + quad * 16);
#pragma unroll
        for (int mt = 0; mt < 4; ++mt) {
#pragma unroll
            for (int nt = 0; nt < 4; ++nt) {
                f32x4 d = __builtin_amdgcn_mfma_f32_16x16x32_bf16(afr[mt], bfr[nt], zero, 0, 0, 0);
#pragma unroll
                for (int rr = 0; rr < 4; ++rr) {
                    const float a = d[rr];
                    s[nt] += a;
                    ss[nt] = fmaf(a, a, ss[nt]);
                }
            }
        }
    }
#pragma unroll
    for (int off = 16; off < 64; off <<= 1)
#pragma unroll
        for (int nt = 0; nt < 4; ++nt) {
            s[nt]  += __shfl_xor(s[nt], off, 64);
            ss[nt] += __shfl_xor(ss[nt], off, 64);
        }
    if (threadIdx.x < 2 * F2) red[threadIdx.x] = 0.f;
    __syncthreads();
    if (quad == 0) {
#pragma unroll
        for (int nt = 0; nt < 4; ++nt) {
            atomicAdd(&red[nt * 16 + m16], s[nt]);
            atomicAdd(&red[F2 + nt * 16 + m16], ss[nt]);
        }
    }
    __syncthreads();
    if (threadIdx.x < 2 * F2)
        atomicAdd(&ws2rep[(blockIdx.x & (NREP - 1)) * 128 + threadIdx.x], red[threadIdx.x]);
}

// ---------------- FALLBACK: per-bucket window scatter, recomputing f1 from pts ----------------
__global__ __launch_bounds__(256, 2) void bucket_scatter_gather_kernel(
    const float* __restrict__ pts, const unsigned int* __restrict__ pairpk,
    const float* __restrict__ w2,
    const float* __restrict__ g2, const float* __restrict__ be2,
    const float* __restrict__ ws, const float* __restrict__ ws2rep,
    const int* __restrict__ offsets,
    unsigned int* __restrict__ out, int nseg, float invN)
{
    __shared__ unsigned int win[NSEGB * WSTRIDE];
    __shared__ __align__(16) unsigned char stag[4][64 * ROWB];
    __shared__ int segl[4][64];

    const int b = blockIdx.x;
    const int start = offsets[b], end = offsets[b + 1];
    const int tid = threadIdx.x;
    const int lane = tid & 63, wv = tid >> 6;
    const int quad = lane >> 4, m16 = lane & 15;

    for (int t = tid; t < NSEGB * WSTRIDE; t += 256) win[t] = 0u;

    bf16x8 bfr[4];
#pragma unroll
    for (int nt = 0; nt < 4; ++nt)
#pragma unroll
        for (int j = 0; j < 8; ++j)
            bfr[nt][j] = (short)f2bf(w2[(quad * 8 + j) * F2 + nt * 16 + m16]);
    float sc2f[4], shb[4];
#pragma unroll
    for (int nt = 0; nt < 4; ++nt) {
        const int f = nt * 16 + m16;
        float S = 0.f, SS = 0.f;
#pragma unroll
        for (int r = 0; r < NREP; ++r) {
            S  += ws2rep[r * 128 + f];
            SS += ws2rep[r * 128 + 64 + f];
        }
        const float mean_a = S * invN;
        const float var    = SS * invN - mean_a * mean_a;
        const float sc     = g2[f] * rsqrtf(var + EPS);
        sc2f[nt] = sc;
        shb[nt]  = be2[f] - mean_a * sc;
    }
    const float* wl  = ws + WS_W1P;
    const float* sh1 = ws + WS_SH1;
    const f32x4 zero = {0.f, 0.f, 0.f, 0.f};
    __syncthreads();

    const int nch = (end - start + 63) >> 6;
    unsigned char* myst = stag[wv];
    for (int c = wv; c < nch; c += 4) {
        const int cbase = start + c * 64;
        const int sp = cbase + lane;
        unsigned int pk[16];
        int sl = -1;
        if (sp < end) {
            const unsigned int v = pairpk[sp];
            f1_row_bf16(pts + (size_t)(v >> SHIFT) * NIN, wl, sh1, pk);
            sl = (int)(v & (NSEGB - 1));
        } else {
#pragma unroll
            for (int q = 0; q < 16; ++q) pk[q] = 0u;
        }
        segl[wv][lane] = sl;
        uint4* wrow = (uint4*)(myst + lane * ROWB);
#pragma unroll
        for (int cidx = 0; cidx < 4; ++cidx)
            wrow[cidx] = make_uint4(pk[4*cidx+0], pk[4*cidx+1], pk[4*cidx+2], pk[4*cidx+3]);

        bf16x8 afr[4];
#pragma unroll
        for (int mt = 0; mt < 4; ++mt)
            afr[mt] = *(const bf16x8*)(myst + (mt * 16 + m16) * ROWB + quad * 16);
#pragma unroll
        for (int mt = 0; mt < 4; ++mt) {
            f32x4 d[4];
#pragma unroll
            for (int nt = 0; nt < 4; ++nt)
                d[nt] = __builtin_amdgcn_mfma_f32_16x16x32_bf16(afr[mt], bfr[nt], zero, 0, 0, 0);
#pragma unroll
            for (int rr = 0; rr < 4; ++rr) {
                const int sl2 = segl[wv][mt * 16 + quad * 4 + rr];
                if (sl2 >= 0) {
#pragma unroll
                    for (int nt = 0; nt < 4; ++nt) {
                        const float vv = fmaf(d[nt][rr], sc2f[nt], shb[nt]);
                        if (vv > 0.f)
                            atomicMax(&win[sl2 * WSTRIDE + nt * 16 + m16], __float_as_uint(vv));
                    }
                }
            }
        }
    }
    __syncthreads();
    const int segbase = b << SHIFT;
    const int rows = min(NSEGB, nseg - segbase);
    for (int t = tid; t < rows * 64; t += 256)
        out[(size_t)(segbase + (t >> 6)) * 64 + (t & 63)] = win[(t >> 6) * WSTRIDE + (t & 63)];
}

extern "C" void kernel_launch(void* const* d_in, const int* in_sizes, int n_in,
                              void* d_out, int out_size, void* d_ws, size_t ws_size,
                              hipStream_t stream)
{
    const float* pts = (const float*)d_in[0];
    const int*   idx = (const int*)d_in[1];
    const float* w1  = (const float*)d_in[3];
    const float* b1  = (const float*)d_in[4];
    const float* g1  = (const float*)d_in[5];
    const float* be1 = (const float*)d_in[6];
    const float* w2  = (const float*)d_in[7];
    const float* g2  = (const float*)d_in[9];
    const float* be2 = (const float*)d_in[10];

    const int N = in_sizes[0] / NIN;
    const int nseg = out_size / F2;
    int nb = (nseg + NSEGB - 1) >> SHIFT;
    if (nb > NBMAX) nb = NBMAX;
    const int nbin = (N + BT_BIN - 1) / BT_BIN;
    const float invN = 1.0f / (float)N;

    char* base = (char*)d_ws;
    const size_t f1bytes   = (size_t)N * 64;
    const size_t pairbytes = (size_t)N * 4;   // packed (i<<SHIFT)|sl
    const size_t rankbytes = (size_t)N * 4;
    const size_t repbytes  = (size_t)NREP * 192 * 4;           // wsrep(64)+ws2rep(128)
    const size_t blkbytes  = (size_t)nb * nbin * 4;
    const size_t tailbytes = 4096 + repbytes + blkbytes +
                             ((size_t)NBMAX + 1 + NBMAX) * 4 + 256;
    const size_t need_main = f1bytes + pairbytes + rankbytes + tailbytes;

    // fused pass A grid: >= nbin so every count slice is covered; 1024 = 4 blocks/CU
    int gA = 1024;
    if (gA < nbin) gA = nbin;

    if (ws_size >= need_main) {
        // ---- main path ----
        uint4*        f1buf   = (uint4*)base;
        unsigned int* pairpk  = (unsigned int*)(base + f1bytes);
        int*          rank    = (int*)(base + f1bytes + pairbytes);
        char*         tail    = base + f1bytes + pairbytes + rankbytes;
        float*        ws      = (float*)tail;
        float*        wsrep   = (float*)(tail + 4096);
        float*        ws2rep  = wsrep + NREP * 64;
        int*          blkcnt  = (int*)(tail + 4096 + repbytes);
        int*          rowsum  = (int*)(tail + 4096 + repbytes + blkbytes);
        int*          offsets = rowsum + NBMAX;

        hipMemsetAsync(wsrep, 0, repbytes, stream);

        moments_count_kernel<<<gA, 256, 0, stream>>>(pts, idx, wsrep, rank, blkcnt, N, nb, nbin);
        scan_finalize1_kernel<<<nb + 1, 256, 0, stream>>>(
            w1, b1, g1, be1, wsrep, ws, invN, blkcnt, rowsum, nbin);
        offsets_scan_kernel<<<1, 1024, 0, stream>>>(rowsum, offsets, nb);
        f1stats_kernel<<<1792, 256, 0, stream>>>(pts, w2, ws, ws2rep, f1buf, N);
        binning_kernel<<<nbin, 256, 0, stream>>>(idx, rank, blkcnt, offsets, pairpk, N, nb, nbin);
        bucket_scatter_kernel<<<nb, 256, 0, stream>>>(
            f1buf, pairpk, w2, g2, be2, ws2rep, offsets,
            (unsigned int*)d_out, nseg, invN);
    } else {
        // ---- fallback: no f1 materialization ----
        unsigned int* pairpk  = (unsigned int*)base;
        int*          rank    = (int*)(base + pairbytes);
        char*         tail    = base + pairbytes + rankbytes;
        float*        ws      = (float*)tail;
        float*        wsrep   = (float*)(tail + 4096);
        float*        ws2rep  = wsrep + NREP * 64;
        int*          blkcnt  = (int*)(tail + 4096 + repbytes);
        int*          rowsum  = (int*)(tail + 4096 + repbytes + blkbytes);
        int*          offsets = rowsum + NBMAX;

        hipMemsetAsync(wsrep, 0, repbytes, stream);

        moments_count_kernel<<<gA, 256, 0, stream>>>(pts, idx, wsrep, rank, blkcnt, N, nb, nbin);
        scan_finalize1_kernel<<<nb + 1, 256, 0, stream>>>(
            w1, b1, g1, be1, wsrep, ws, invN, blkcnt, rowsum, nbin);
        offsets_scan_kernel<<<1, 1024, 0, stream>>>(rowsum, offsets, nb);
        binning_kernel<<<nbin, 256, 0, stream>>>(idx, rank, blkcnt, offsets, pairpk, N, nb, nbin);
        stats2_kernel<<<1024, 256, 0, stream>>>(pts, w2, ws, ws2rep, N);
        bucket_scatter_gather_kernel<<<nb, 256, 0, stream>>>(
            pts, pairpk, w2, g2, be2, ws, ws2rep, offsets,
            (unsigned int*)d_out, nseg, invN);
    }
}